// Round 9
// baseline (417.160 us; speedup 1.0000x reference)
//
#include <hip/hip_runtime.h>
#include <hip/hip_bf16.h>

#define NNODES 50000
#define NEDGES 800000
#define HID 256
#define BN_EPS 1e-5f
#define SCAN_B ((NNODES + 255) / 256)   // 196 blocks

typedef __attribute__((ext_vector_type(8))) short short8v;
typedef __attribute__((ext_vector_type(4))) float f32x4;
typedef __attribute__((ext_vector_type(2))) float f32x2;

__device__ inline void load_lds16(const void* g, void* l) {
    __builtin_amdgcn_global_load_lds(
        (const __attribute__((address_space(1))) unsigned int*)g,
        (__attribute__((address_space(3))) unsigned int*)l, 16, 0, 0);
}

// ---------------- CSR build ----------------
__global__ void k_countrank(const int* __restrict__ ei, int* __restrict__ cnt,
                            int* __restrict__ rank, int nE) {
    int e = blockIdx.x * blockDim.x + threadIdx.x;
    if (e < nE) rank[e] = atomicAdd(&cnt[ei[nE + e]], 1);
}

__global__ void k_bsum(const int* __restrict__ cnt, int* __restrict__ loc,
                       int* __restrict__ bsum, int n) {
    __shared__ int sh[256];
    int tid = threadIdx.x;
    int i = blockIdx.x * 256 + tid;
    int v = (i < n) ? cnt[i] : 0;
    sh[tid] = v;
    __syncthreads();
    for (int off = 1; off < 256; off <<= 1) {
        int t = (tid >= off) ? sh[tid - off] : 0;
        __syncthreads();
        sh[tid] += t;
        __syncthreads();
    }
    if (i < n) loc[i] = sh[tid] - v;
    if (tid == 255) bsum[blockIdx.x] = sh[255];
}

__global__ void k_bscan(int* __restrict__ bsum, int nb) {
    __shared__ int sh[256];
    int tid = threadIdx.x;
    int v = (tid < nb) ? bsum[tid] : 0;
    sh[tid] = v;
    __syncthreads();
    for (int off = 1; off < 256; off <<= 1) {
        int t = (tid >= off) ? sh[tid - off] : 0;
        __syncthreads();
        sh[tid] += t;
        __syncthreads();
    }
    if (tid < nb) bsum[tid] = sh[tid] - v;
}

__global__ void k_addoff(const int* __restrict__ loc, const int* __restrict__ bsum,
                         int* __restrict__ rowptr, int n, int nE) {
    int i = blockIdx.x * 256 + threadIdx.x;
    if (i < n) rowptr[i] = loc[i] + bsum[blockIdx.x];
    if (i == 0) rowptr[n] = nE;
}

__global__ void k_fill2(const int* __restrict__ ei, const int* __restrict__ rowptr,
                        const int* __restrict__ rank, int* __restrict__ col, int nE) {
    int e = blockIdx.x * blockDim.x + threadIdx.x;
    if (e < nE) col[rowptr[ei[nE + e]] + rank[e]] = ei[e];
}

// ---------------- fused prep: cast x->bf16+fp8, transpose weights, zero cnt
#define PREP_CAST 1600000
#define PREP_TR   327680
__global__ void k_prep(const float* __restrict__ x,
                       __hip_bfloat16* __restrict__ xb, unsigned char* __restrict__ x8,
                       const float* __restrict__ s0, const float* __restrict__ s1,
                       const float* __restrict__ s2, const float* __restrict__ s3,
                       const float* __restrict__ s4, const float* __restrict__ s5,
                       __hip_bfloat16* __restrict__ d0, __hip_bfloat16* __restrict__ d1,
                       __hip_bfloat16* __restrict__ d2, __hip_bfloat16* __restrict__ d3,
                       __hip_bfloat16* __restrict__ d4, __hip_bfloat16* __restrict__ d5,
                       int* __restrict__ cnt) {
    int f = blockIdx.x * blockDim.x + threadIdx.x;
    if (f < PREP_CAST) {
        float4 v = *(const float4*)(x + f * 4);
        union { uint2 u; unsigned short s[4]; } ob;
        ob.s[0] = __bfloat16_as_ushort(__float2bfloat16(v.x));
        ob.s[1] = __bfloat16_as_ushort(__float2bfloat16(v.y));
        ob.s[2] = __bfloat16_as_ushort(__float2bfloat16(v.z));
        ob.s[3] = __bfloat16_as_ushort(__float2bfloat16(v.w));
        *(uint2*)(xb + f * 4) = ob.u;
        int p = __builtin_amdgcn_cvt_pk_fp8_f32(v.x, v.y, 0, false);
        p = __builtin_amdgcn_cvt_pk_fp8_f32(v.z, v.w, p, true);
        *(int*)(x8 + f * 4) = p;
    } else if (f < PREP_CAST + PREP_TR) {
        int r = f - PREP_CAST;
        const float* src; __hip_bfloat16* dst; int K; int i;
        if (r < 65536) {
            K = 128;
            if (r < 32768) { src = s0; dst = d0; i = r; }
            else           { src = s1; dst = d1; i = r - 32768; }
        } else {
            K = 256;
            int q = r - 65536;
            int wsel = q >> 16;
            i = q & 65535;
            src = (wsel == 0) ? s2 : (wsel == 1) ? s3 : (wsel == 2) ? s4 : s5;
            dst = (wsel == 0) ? d2 : (wsel == 1) ? d3 : (wsel == 2) ? d4 : d5;
        }
        int k = i >> 8;
        int nn = i & 255;
        dst[nn * K + k] = __float2bfloat16(src[i]);
    } else {
        int i = f - PREP_CAST - PREP_TR;
        if (i < NNODES) cnt[i] = 0;
    }
}

// ---------------- mean aggregation over fp8 table -> bf16 mean ----------
template <int D, int U>
__global__ void k_meanf8(const unsigned char* __restrict__ x8,
                         const int* __restrict__ rowptr, const int* __restrict__ col,
                         __hip_bfloat16* __restrict__ mean, int n) {
    constexpr int CPL = D / 16;
    constexpr int R = 64 / CPL;
    int gw = (blockIdx.x * blockDim.x + threadIdx.x) >> 6;
    int lane = threadIdx.x & 63;
    if (gw >= n) return;
    int beg = rowptr[gw], end = rowptr[gw + 1];
    int sub = lane / CPL;
    int fpos = lane % CPL;
    const uint4* base = (const uint4*)x8;

    float acc[16];
#pragma unroll
    for (int j = 0; j < 16; j++) acc[j] = 0.f;

    for (int p0 = beg; p0 < end; p0 += U * R) {
        int idx[U]; bool ok[U];
#pragma unroll
        for (int u = 0; u < U; u++) {
            int p = p0 + u * R + sub;
            ok[u] = (p < end);
            idx[u] = ok[u] ? col[p] : 0;
        }
        uint4 v[U];
#pragma unroll
        for (int u = 0; u < U; u++) {
            uint4 t = {0u, 0u, 0u, 0u};
            if (ok[u]) t = base[(size_t)idx[u] * CPL + fpos];
            v[u] = t;
        }
#pragma unroll
        for (int u = 0; u < U; u++) {
            const unsigned int uu[4] = {v[u].x, v[u].y, v[u].z, v[u].w};
#pragma unroll
            for (int q = 0; q < 4; q++) {
                f32x2 lo = __builtin_amdgcn_cvt_pk_f32_fp8(uu[q], false);
                f32x2 hi = __builtin_amdgcn_cvt_pk_f32_fp8(uu[q], true);
                acc[4 * q + 0] += lo.x;
                acc[4 * q + 1] += lo.y;
                acc[4 * q + 2] += hi.x;
                acc[4 * q + 3] += hi.y;
            }
        }
    }

    if constexpr (R >= 8) {
#pragma unroll
        for (int j = 0; j < 16; j++) acc[j] += __shfl_xor(acc[j], 8, 64);
    }
#pragma unroll
    for (int j = 0; j < 16; j++) acc[j] += __shfl_xor(acc[j], 16, 64);
#pragma unroll
    for (int j = 0; j < 16; j++) acc[j] += __shfl_xor(acc[j], 32, 64);

    if (sub == 0) {
        float inv = (end > beg) ? 1.f / (float)(end - beg) : 0.f;
        union { uint4 v[2]; unsigned short s[16]; } o;
#pragma unroll
        for (int j = 0; j < 16; j++)
            o.s[j] = __bfloat16_as_ushort(__float2bfloat16(acc[j] * inv));
        uint4* dst = (uint4*)(mean + (size_t)gw * D + fpos * 16);
        dst[0] = o.v[0];
        dst[1] = o.v[1];
    }
}

// ---------------- fused GEMM + BN (+ReLU): 64x256 tile, swizzled LDS -------
// out[n,256] = act( (A1@W1 + A2@W2 + bl - rm) * scale + shift )
// LDS chunk swizzle: row R's 16B chunk q stored at position q ^ ((R>>1)&3).
// Staging keeps dst linear (global_load_lds needs base+lane*16); the SOURCE
// address is permuted instead. Read side: chunk pos = quad ^ ((ml>>1)&3),
// giving 2-way bank aliasing (free) instead of 8-way.
template <int K, typename OutT, int RELU, int W8>
__launch_bounds__(256, 4)
__global__ void k_gemm3(const __hip_bfloat16* __restrict__ A1,
                        const __hip_bfloat16* __restrict__ A2,
                        const __hip_bfloat16* __restrict__ W1t,
                        const __hip_bfloat16* __restrict__ W2t,
                        const float* __restrict__ bl,
                        const float* __restrict__ g,
                        const float* __restrict__ bb,
                        const float* __restrict__ rm,
                        const float* __restrict__ rv,
                        OutT* __restrict__ out, unsigned char* __restrict__ out8,
                        int n) {
    __shared__ __hip_bfloat16 As1[64 * 32];    // 4 KB
    __shared__ __hip_bfloat16 As2[64 * 32];    // 4 KB
    __shared__ __hip_bfloat16 Bs1[256 * 32];   // 16 KB
    __shared__ __hip_bfloat16 Bs2[256 * 32];   // 16 KB
    int tid = threadIdx.x;
    int lane = tid & 63;
    int w = tid >> 6;              // wave: cols [w*64, +64)
    int quad = lane >> 4;
    int ml = lane & 15;
    int rowBase = blockIdx.x * 64;

    f32x4 acc[4][4];
#pragma unroll
    for (int i = 0; i < 4; i++)
#pragma unroll
        for (int t = 0; t < 4; t++) acc[i][t] = {0.f, 0.f, 0.f, 0.f};

    int srow = tid >> 2;                 // 0..63 (staging row)
    int c4 = tid & 3;                    // chunk position 0..3
    int sswz = c4 ^ ((srow >> 1) & 3);   // source chunk for swizzled store
    int rswz = quad ^ ((ml >> 1) & 3);   // chunk position for reads

    int grow = rowBase + srow; if (grow >= n) grow = n - 1;

    for (int k0 = 0; k0 < K; k0 += 32) {
        __syncthreads();
        load_lds16((const char*)(A1 + (size_t)grow * K + k0) + sswz * 16,
                   (char*)As1 + srow * 64 + c4 * 16);
        load_lds16((const char*)(A2 + (size_t)grow * K + k0) + sswz * 16,
                   (char*)As2 + srow * 64 + c4 * 16);
#pragma unroll
        for (int h = 0; h < 4; h++) {
            int c = srow + h * 64;   // (c>>1)&3 == (srow>>1)&3 since h*64>>1 ≡ 0 mod 4
            load_lds16((const char*)(W1t + (size_t)c * K + k0) + sswz * 16,
                       (char*)Bs1 + c * 64 + c4 * 16);
            load_lds16((const char*)(W2t + (size_t)c * K + k0) + sswz * 16,
                       (char*)Bs2 + c * 64 + c4 * 16);
        }
        __syncthreads();

        short8v af1[4], af2[4];
#pragma unroll
        for (int i = 0; i < 4; i++) {
            af1[i] = *(const short8v*)(As1 + (i * 16 + ml) * 32 + rswz * 8);
            af2[i] = *(const short8v*)(As2 + (i * 16 + ml) * 32 + rswz * 8);
        }
#pragma unroll
        for (int t = 0; t < 4; t++) {
            int brow = w * 64 + t * 16 + ml;   // (brow>>1)&3 == (ml>>1)&3
            short8v bf1 = *(const short8v*)(Bs1 + brow * 32 + rswz * 8);
            short8v bf2 = *(const short8v*)(Bs2 + brow * 32 + rswz * 8);
#pragma unroll
            for (int i = 0; i < 4; i++) {
                acc[i][t] = __builtin_amdgcn_mfma_f32_16x16x32_bf16(af1[i], bf1, acc[i][t], 0, 0, 0);
                acc[i][t] = __builtin_amdgcn_mfma_f32_16x16x32_bf16(af2[i], bf2, acc[i][t], 0, 0, 0);
            }
        }
    }

#pragma unroll
    for (int t = 0; t < 4; t++) {
        int c = w * 64 + t * 16 + ml;
        float sv = g[c] * rsqrtf(rv[c] + BN_EPS);
        float tv = (bl[c] - rm[c]) * sv + bb[c];
#pragma unroll
        for (int i = 0; i < 4; i++) {
            int row0 = rowBase + i * 16 + quad * 4;
#pragma unroll
            for (int r = 0; r < 4; r++) {
                int row = row0 + r;
                if (row < n) {
                    float v = acc[i][t][r] * sv + tv;
                    if (RELU) v = fmaxf(v, 0.f);
                    if constexpr (sizeof(OutT) == 2)
                        out[(size_t)row * HID + c] = (OutT)__float2bfloat16(v);
                    else
                        out[(size_t)row * HID + c] = (OutT)v;
                    if constexpr (W8) {
                        int p = __builtin_amdgcn_cvt_pk_fp8_f32(v, v, 0, false);
                        out8[(size_t)row * HID + c] = (unsigned char)(p & 0xFF);
                    }
                }
            }
        }
    }
}

extern "C" void kernel_launch(void* const* d_in, const int* in_sizes, int n_in,
                              void* d_out, int out_size, void* d_ws, size_t ws_size,
                              hipStream_t stream) {
    const float* x = (const float*)d_in[0];
    const int* ei = (const int*)d_in[1];
    const float *Wl[3], *blv[3], *Wr[3], *g[3], *bb[3], *rm[3], *rv[3];
    for (int i = 0; i < 3; i++) {
        int b = 2 + i * 7;
        Wl[i]  = (const float*)d_in[b + 0];
        blv[i] = (const float*)d_in[b + 1];
        Wr[i]  = (const float*)d_in[b + 2];
        g[i]   = (const float*)d_in[b + 3];
        bb[i]  = (const float*)d_in[b + 4];
        rm[i]  = (const float*)d_in[b + 5];
        rv[i]  = (const float*)d_in[b + 6];
    }

    // scratch inside d_out (fully overwritten by the final GEMM):
    char* ob = (char*)d_out;
    __hip_bfloat16* xb = (__hip_bfloat16*)ob;                              // 12.8 MB
    __hip_bfloat16* h0 = (__hip_bfloat16*)(ob + (size_t)NNODES * 128 * 2); // 25.6 MB

    char* w = (char*)d_ws;
    size_t off = 0;
    auto alloc = [&](size_t bytes) {
        void* p = w + off;
        off += (bytes + 255) & ~(size_t)255;
        return p;
    };
    int* rowptr = (int*)alloc((NNODES + 1) * sizeof(int));
    int* cnt    = (int*)alloc(NNODES * sizeof(int));
    int* loc    = (int*)alloc(NNODES * sizeof(int));
    int* bsum   = (int*)alloc(SCAN_B * sizeof(int));
    int* rank   = (int*)alloc(NEDGES * sizeof(int));
    int* col    = (int*)alloc(NEDGES * sizeof(int));
    __hip_bfloat16* meanb = (__hip_bfloat16*)alloc((size_t)NNODES * HID * 2);
    __hip_bfloat16* h1    = (__hip_bfloat16*)alloc((size_t)NNODES * HID * 2);
    unsigned char* x8   = (unsigned char*)alloc((size_t)NNODES * 128);
    unsigned char* h0f8 = (unsigned char*)alloc((size_t)NNODES * HID);
    unsigned char* h1f8 = (unsigned char*)alloc((size_t)NNODES * HID);
    __hip_bfloat16* Wt[6];
    int Ks[6] = {128, 128, 256, 256, 256, 256};
    for (int i = 0; i < 6; i++) Wt[i] = (__hip_bfloat16*)alloc((size_t)Ks[i] * HID * 2);

    // fused prep: cast x (bf16 + fp8), transpose weights, zero cnt
    int prepTotal = PREP_CAST + PREP_TR + NNODES;
    k_prep<<<(prepTotal + 255) / 256, 256, 0, stream>>>(
        x, xb, x8, Wl[0], Wr[0], Wl[1], Wr[1], Wl[2], Wr[2],
        Wt[0], Wt[1], Wt[2], Wt[3], Wt[4], Wt[5], cnt);

    // CSR build
    k_countrank<<<(NEDGES + 255) / 256, 256, 0, stream>>>(ei, cnt, rank, NEDGES);
    k_bsum<<<SCAN_B, 256, 0, stream>>>(cnt, loc, bsum, NNODES);
    k_bscan<<<1, 256, 0, stream>>>(bsum, SCAN_B);
    k_addoff<<<SCAN_B, 256, 0, stream>>>(loc, bsum, rowptr, NNODES, NEDGES);
    k_fill2<<<(NEDGES + 255) / 256, 256, 0, stream>>>(ei, rowptr, rank, col, NEDGES);

    int meanBlocks = (NNODES * 64 + 255) / 256;      // one wave per node
    int gemmBlocks = (NNODES + 63) / 64;             // 782

    // layer 0 (K=128): fp8 gather
    k_meanf8<128, 2><<<meanBlocks, 256, 0, stream>>>(x8, rowptr, col, meanb, NNODES);
    k_gemm3<128, __hip_bfloat16, 1, 1><<<gemmBlocks, 256, 0, stream>>>(meanb, xb, Wt[0], Wt[1],
        blv[0], g[0], bb[0], rm[0], rv[0], h0, h0f8, NNODES);

    // layer 1 (K=256)
    k_meanf8<256, 4><<<meanBlocks, 256, 0, stream>>>(h0f8, rowptr, col, meanb, NNODES);
    k_gemm3<256, __hip_bfloat16, 1, 1><<<gemmBlocks, 256, 0, stream>>>(meanb, h0, Wt[2], Wt[3],
        blv[1], g[1], bb[1], rm[1], rv[1], h1, h1f8, NNODES);

    // layer 2 (K=256, no relu) -> f32 d_out
    k_meanf8<256, 4><<<meanBlocks, 256, 0, stream>>>(h1f8, rowptr, col, meanb, NNODES);
    k_gemm3<256, float, 0, 0><<<gemmBlocks, 256, 0, stream>>>(meanb, h1, Wt[4], Wt[5],
        blv[2], g[2], bb[2], rm[2], rv[2], (float*)d_out, (unsigned char*)nullptr, NNODES);
}